// Round 4
// baseline (1193.670 us; speedup 1.0000x reference)
//
#include <hip/hip_runtime.h>
#include <math.h>

#define NEXP 8
#define TTOK 8192
#define DEMB 1024
#define HFF  4096

// ws layout (bytes)
#define OFF_CNT   0
#define OFF_OFFS  64
#define OFF_PTOK  1024
#define OFF_PW    (OFF_PTOK + NEXP*TTOK*4)
#define OFF_XB    (OFF_PW + NEXP*TTOK*4)
#define OFF_WB    (OFF_XB + (size_t)TTOK*DEMB*2)

typedef short bf16x8 __attribute__((ext_vector_type(8)));
typedef float f32x4 __attribute__((ext_vector_type(4)));

// per-buffer LDS: A 256x64 bf16 (32KB) + B 128x64 bf16 (16KB) = 48KB; 3 buffers
#define BUFB 49152

__device__ __forceinline__ unsigned short f2bf(float f) {
  union { float f; unsigned int u; } v; v.f = f;
  unsigned int r = v.u + 0x7fffu + ((v.u >> 16) & 1u);
  return (unsigned short)(r >> 16);
}

__device__ __forceinline__ void gll16(const void* g, void* l) {
  __builtin_amdgcn_global_load_lds(
      (const __attribute__((address_space(1))) unsigned int*)g,
      (__attribute__((address_space(3))) unsigned int*)l, 16, 0, 0);
}

// ---------------- weights fp32 -> bf16 ----------------
__global__ void k_convert_w(const float* __restrict__ w, uint4* __restrict__ wb) {
  size_t i = (size_t)blockIdx.x * 256 + threadIdx.x;
  float4 a = ((const float4*)w)[2 * i];
  float4 b = ((const float4*)w)[2 * i + 1];
  uint4 o;
  o.x = (unsigned)f2bf(a.x) | ((unsigned)f2bf(a.y) << 16);
  o.y = (unsigned)f2bf(a.z) | ((unsigned)f2bf(a.w) << 16);
  o.z = (unsigned)f2bf(b.x) | ((unsigned)f2bf(b.y) << 16);
  o.w = (unsigned)f2bf(b.z) | ((unsigned)f2bf(b.w) << 16);
  wb[i] = o;
}

// ---------------- gating + top-2 + routing + X->bf16 ----------------
__global__ __launch_bounds__(256) void k_gate(
    const float* __restrict__ x, const float* __restrict__ wg,
    int* __restrict__ cnt, int* __restrict__ ptok, float* __restrict__ pw,
    unsigned short* __restrict__ xb) {
  __shared__ float wgs[NEXP * DEMB];
  int tid = threadIdx.x;
  for (int i = tid; i < NEXP * DEMB / 4; i += 256)
    ((float4*)wgs)[i] = ((const float4*)wg)[i];
  __syncthreads();
  int lane = tid & 63;
  int t = blockIdx.x * 4 + (tid >> 6);
  const float* xr = x + (size_t)t * DEMB;
  unsigned short* xbr = xb + (size_t)t * DEMB;
  float acc[NEXP];
#pragma unroll
  for (int e = 0; e < NEXP; ++e) acc[e] = 0.f;
#pragma unroll
  for (int j = 0; j < 4; ++j) {
    int d = j * 256 + lane * 4;
    float4 v = *(const float4*)(xr + d);
    ushort4 o;
    o.x = f2bf(v.x); o.y = f2bf(v.y); o.z = f2bf(v.z); o.w = f2bf(v.w);
    *(ushort4*)(xbr + d) = o;
#pragma unroll
    for (int e = 0; e < NEXP; ++e) {
      float4 w = *(const float4*)(wgs + e * DEMB + d);
      acc[e] += v.x * w.x + v.y * w.y + v.z * w.z + v.w * w.w;
    }
  }
#pragma unroll
  for (int e = 0; e < NEXP; ++e) {
#pragma unroll
    for (int off = 32; off > 0; off >>= 1) acc[e] += __shfl_xor(acc[e], off);
  }
  if (lane == 0) {
    float b0 = -1e30f; int i0 = 0;
#pragma unroll
    for (int e = 0; e < NEXP; ++e) if (acc[e] > b0) { b0 = acc[e]; i0 = e; }
    float b1 = -1e30f; int i1 = 0;
#pragma unroll
    for (int e = 0; e < NEXP; ++e) if (e != i0 && acc[e] > b1) { b1 = acc[e]; i1 = e; }
    float ex = expf(b1 - b0);
    float s  = 1.f + ex;
    int s0 = atomicAdd(&cnt[i0], 1);
    ptok[i0 * TTOK + s0] = t; pw[i0 * TTOK + s0] = 1.f / s;
    int s1 = atomicAdd(&cnt[i1], 1);
    ptok[i1 * TTOK + s1] = t; pw[i1 * TTOK + s1] = ex / s;
  }
}

__global__ void k_scan(const int* __restrict__ cnt, int* __restrict__ offs) {
  if (threadIdx.x == 0) {
    int s = 0;
    for (int e = 0; e < NEXP; ++e) { offs[e] = s; s += cnt[e]; }
  }
}

// --- shared schedule idioms ---
#define GATE6()  { asm volatile("s_waitcnt vmcnt(6)" ::: "memory"); \
                   __builtin_amdgcn_s_barrier(); __builtin_amdgcn_sched_barrier(0); }
#define GATE0()  { asm volatile("s_waitcnt vmcnt(0)" ::: "memory"); \
                   __builtin_amdgcn_s_barrier(); __builtin_amdgcn_sched_barrier(0); }
#define LGKM0()  { asm volatile("s_waitcnt lgkmcnt(0)" ::: "memory"); \
                   __builtin_amdgcn_sched_barrier(0); }

// ================ GEMM1: h = silu(X@W1^T)*(X@W3^T) -> Hb ================
// BM=256 (tokens), B-hat=128 rows = per-wn {16 W1-cols,16 W3-cols}, BK=64, NT=16.
// 512 thr = 8 waves (2M x 4N); per-wave out 128 rows x (16 u-cols + 16 v-cols).
__global__ __launch_bounds__(512, 2) void k_gemm1(
    const unsigned short* __restrict__ Xb, const unsigned short* __restrict__ w1b,
    const unsigned short* __restrict__ w3b, const int* __restrict__ cnt,
    const int* __restrict__ offs, const int* __restrict__ ptok,
    unsigned short* __restrict__ Hb, int e_sel, int mbase, int mTiles) {
  int nwg = gridDim.x;
  int orig = blockIdx.x;
  int idp = (orig & 7) * (nwg >> 3) + (orig >> 3);
  int mt, e, nt;
  if (e_sel >= 0) { e = e_sel; mt = idp % mTiles; nt = idp / mTiles; }
  else { mt = idp % mTiles; e = (idp / mTiles) % NEXP; nt = idp / (mTiles * NEXP); }
  int ce = cnt[e];
  int m0 = mbase + mt * 256;
  if (m0 >= ce) return;
  int h0 = nt * 64;                                   // 64 hff cols per tile
  int hb = (e_sel >= 0) ? -mbase : offs[e];
  size_t eo = (size_t)((e_sel >= 0) ? 0 : e) * HFF * DEMB;
  const unsigned short* w1e = w1b + eo;
  const unsigned short* w3e = w3b + eo;

  __shared__ __align__(16) unsigned char sm[3 * BUFB];
  int tid = threadIdx.x, lane = tid & 63, wid = tid >> 6;
  int wm = wid >> 2, wn = wid & 3;

  // staging sources (granule-XOR pre-swizzled; involution with read side)
  const unsigned short* sA[4];
#pragma unroll
  for (int i = 0; i < 4; ++i) {
    int c = i * 512 + tid;              // 0..2047
    int row = c >> 3, g = c & 7;
    int slot = m0 + row; slot = slot < ce ? slot : ce - 1;
    int tok = ptok[e * TTOK + slot];
    sA[i] = Xb + (size_t)tok * DEMB + ((g ^ (row & 7)) * 8);
  }
  const unsigned short* sB[2];
#pragma unroll
  for (int i = 0; i < 2; ++i) {
    int c = i * 512 + tid;              // 0..1023
    int br = c >> 3, g = c & 7;
    int wn_ = br >> 5, cc = br & 15, mat = (br >> 4) & 1;
    int hr = h0 + wn_ * 16 + cc;
    const unsigned short* wsrc = mat ? w3e : w1e;
    sB[i] = wsrc + (size_t)hr * DEMB + ((g ^ (br & 7)) * 8);
  }

#define G1_STAGE_P0(pb, tt) { size_t o = (size_t)(tt) * 64; \
    gll16(sA[0] + o, sm + (pb) * BUFB + 0 * 8192 + wid * 1024); \
    gll16(sA[1] + o, sm + (pb) * BUFB + 1 * 8192 + wid * 1024); \
    gll16(sA[2] + o, sm + (pb) * BUFB + 2 * 8192 + wid * 1024); }
#define G1_STAGE_P1(pb, tt) { size_t o = (size_t)(tt) * 64; \
    gll16(sA[3] + o, sm + (pb) * BUFB + 3 * 8192 + wid * 1024); \
    gll16(sB[0] + o, sm + (pb) * BUFB + 32768 + wid * 1024); \
    gll16(sB[1] + o, sm + (pb) * BUFB + 32768 + 8192 + wid * 1024); }

  const f32x4 zf = {0.f, 0.f, 0.f, 0.f};
  f32x4 acc[8][2];
#pragma unroll
  for (int a = 0; a < 8; ++a) { acc[a][0] = zf; acc[a][1] = zf; }

  const int NT = DEMB / 64;   // 16
  G1_STAGE_P0(0, 0) G1_STAGE_P1(0, 0)
  G1_STAGE_P0(1, 1) G1_STAGE_P1(1, 1)

  bf16x8 af[4][2], bf[2][2];
  for (int t = 0; t < NT; ++t) {
    if (t < NT - 1) GATE6() else GATE0()
    const unsigned char* Ab = sm + (t % 3) * BUFB;
    const unsigned char* Bb = Ab + 32768;
    int pb = (t + 2) % 3;
    bool st = (t + 2) < NT;
    // ---- phase 0: mr 0-3 ----
#pragma unroll
    for (int mr = 0; mr < 4; ++mr) {
      int r = wm * 128 + mr * 16 + (lane & 15);
#pragma unroll
      for (int ks = 0; ks < 2; ++ks) {
        int kg = ks * 4 + (lane >> 4);
        af[mr][ks] = *(const bf16x8*)(Ab + r * 128 + ((kg ^ (r & 7)) * 16));
      }
    }
#pragma unroll
    for (int nr = 0; nr < 2; ++nr) {
      int br = wn * 32 + nr * 16 + (lane & 15);
#pragma unroll
      for (int ks = 0; ks < 2; ++ks) {
        int kg = ks * 4 + (lane >> 4);
        bf[nr][ks] = *(const bf16x8*)(Bb + br * 128 + ((kg ^ (br & 7)) * 16));
      }
    }
    if (st) G1_STAGE_P0(pb, t + 2)
    LGKM0()
    __builtin_amdgcn_s_setprio(1);
#pragma unroll
    for (int mr = 0; mr < 4; ++mr)
#pragma unroll
      for (int nr = 0; nr < 2; ++nr)
#pragma unroll
        for (int ks = 0; ks < 2; ++ks)
          acc[mr][nr] = __builtin_amdgcn_mfma_f32_16x16x32_bf16(af[mr][ks], bf[nr][ks], acc[mr][nr], 0, 0, 0);
    __builtin_amdgcn_s_setprio(0);
    __builtin_amdgcn_s_barrier();
    // ---- phase 1: mr 4-7 ----
#pragma unroll
    for (int mr = 0; mr < 4; ++mr) {
      int r = wm * 128 + 64 + mr * 16 + (lane & 15);
#pragma unroll
      for (int ks = 0; ks < 2; ++ks) {
        int kg = ks * 4 + (lane >> 4);
        af[mr][ks] = *(const bf16x8*)(Ab + r * 128 + ((kg ^ (r & 7)) * 16));
      }
    }
    if (st) G1_STAGE_P1(pb, t + 2)
    LGKM0()
    __builtin_amdgcn_s_setprio(1);
#pragma unroll
    for (int mr = 0; mr < 4; ++mr)
#pragma unroll
      for (int nr = 0; nr < 2; ++nr)
#pragma unroll
        for (int ks = 0; ks < 2; ++ks)
          acc[4 + mr][nr] = __builtin_amdgcn_mfma_f32_16x16x32_bf16(af[mr][ks], bf[nr][ks], acc[4 + mr][nr], 0, 0, 0);
    __builtin_amdgcn_s_setprio(0);
  }
  // epilogue: u=acc[.][0], v=acc[.][1] share (row,col); col = h0 + wn*16 + (lane&15)
  int col = h0 + wn * 16 + (lane & 15);
#pragma unroll
  for (int mr = 0; mr < 8; ++mr) {
#pragma unroll
    for (int j = 0; j < 4; ++j) {
      int rs = m0 + wm * 128 + mr * 16 + (lane >> 4) * 4 + j;
      if (rs < ce) {
        float u = acc[mr][0][j], v = acc[mr][1][j];
        float h = v * (u / (1.f + __expf(-u)));
        Hb[(size_t)(hb + rs) * HFF + col] = f2bf(h);
      }
    }
  }
#undef G1_STAGE_P0
#undef G1_STAGE_P1
}

// ================ GEMM2: out += gate_w * (H @ W2^T) ================
// BM=256 (rows of Hb), BN=128 (out cols), BK=64, NT=64. Same schedule.
__global__ __launch_bounds__(512, 2) void k_gemm2(
    const unsigned short* __restrict__ Hb, const unsigned short* __restrict__ w2b,
    const int* __restrict__ cnt, const int* __restrict__ offs,
    const int* __restrict__ ptok, const float* __restrict__ pw,
    float* __restrict__ out, int e_sel, int mbase, int mTiles) {
  int nwg = gridDim.x;
  int orig = blockIdx.x;
  int idp = (orig & 7) * (nwg >> 3) + (orig >> 3);
  int mt, e, nt;
  if (e_sel >= 0) { e = e_sel; mt = idp % mTiles; nt = idp / mTiles; }
  else { mt = idp % mTiles; e = (idp / mTiles) % NEXP; nt = idp / (mTiles * NEXP); }
  int ce = cnt[e];
  int m0 = mbase + mt * 256;
  if (m0 >= ce) return;
  int n0 = nt * 128;
  int hb = (e_sel >= 0) ? -mbase : offs[e];
  size_t eo = (size_t)((e_sel >= 0) ? 0 : e) * DEMB * HFF;
  const unsigned short* w2e = w2b + eo;

  __shared__ __align__(16) unsigned char sm[3 * BUFB];
  int tid = threadIdx.x, lane = tid & 63, wid = tid >> 6;
  int wm = wid >> 2, wn = wid & 3;

  const unsigned short* sA[4];
#pragma unroll
  for (int i = 0; i < 4; ++i) {
    int c = i * 512 + tid;
    int row = c >> 3, g = c & 7;
    int slot = m0 + row; slot = slot < ce ? slot : ce - 1;
    sA[i] = Hb + (size_t)(hb + slot) * HFF + ((g ^ (row & 7)) * 8);
  }
  const unsigned short* sB[2];
#pragma unroll
  for (int i = 0; i < 2; ++i) {
    int c = i * 512 + tid;
    int br = c >> 3, g = c & 7;
    sB[i] = w2e + (size_t)(n0 + br) * HFF + ((g ^ (br & 7)) * 8);
  }

#define G2_STAGE_P0(pb, tt) { size_t o = (size_t)(tt) * 64; \
    gll16(sA[0] + o, sm + (pb) * BUFB + 0 * 8192 + wid * 1024); \
    gll16(sA[1] + o, sm + (pb) * BUFB + 1 * 8192 + wid * 1024); \
    gll16(sA[2] + o, sm + (pb) * BUFB + 2 * 8192 + wid * 1024); }
#define G2_STAGE_P1(pb, tt) { size_t o = (size_t)(tt) * 64; \
    gll16(sA[3] + o, sm + (pb) * BUFB + 3 * 8192 + wid * 1024); \
    gll16(sB[0] + o, sm + (pb) * BUFB + 32768 + wid * 1024); \
    gll16(sB[1] + o, sm + (pb) * BUFB + 32768 + 8192 + wid * 1024); }

  const f32x4 zf = {0.f, 0.f, 0.f, 0.f};
  f32x4 acc[8][2];
#pragma unroll
  for (int a = 0; a < 8; ++a) { acc[a][0] = zf; acc[a][1] = zf; }

  const int NT = HFF / 64;   // 64
  G2_STAGE_P0(0, 0) G2_STAGE_P1(0, 0)
  G2_STAGE_P0(1, 1) G2_STAGE_P1(1, 1)

  bf16x8 af[4][2], bf[2][2];
  for (int t = 0; t < NT; ++t) {
    if (t < NT - 1) GATE6() else GATE0()
    const unsigned char* Ab = sm + (t % 3) * BUFB;
    const unsigned char* Bb = Ab + 32768;
    int pb = (t + 2) % 3;
    bool st = (t + 2) < NT;
    // ---- phase 0 ----
#pragma unroll
    for (int mr = 0; mr < 4; ++mr) {
      int r = wm * 128 + mr * 16 + (lane & 15);
#pragma unroll
      for (int ks = 0; ks < 2; ++ks) {
        int kg = ks * 4 + (lane >> 4);
        af[mr][ks] = *(const bf16x8*)(Ab + r * 128 + ((kg ^ (r & 7)) * 16));
      }
    }
#pragma unroll
    for (int nr = 0; nr < 2; ++nr) {
      int br = wn * 32 + nr * 16 + (lane & 15);
#pragma unroll
      for (int ks = 0; ks < 2; ++ks) {
        int kg = ks * 4 + (lane >> 4);
        bf[nr][ks] = *(const bf16x8*)(Bb + br * 128 + ((kg ^ (br & 7)) * 16));
      }
    }
    if (st) G2_STAGE_P0(pb, t + 2)
    LGKM0()
    __builtin_amdgcn_s_setprio(1);
#pragma unroll
    for (int mr = 0; mr < 4; ++mr)
#pragma unroll
      for (int nr = 0; nr < 2; ++nr)
#pragma unroll
        for (int ks = 0; ks < 2; ++ks)
          acc[mr][nr] = __builtin_amdgcn_mfma_f32_16x16x32_bf16(af[mr][ks], bf[nr][ks], acc[mr][nr], 0, 0, 0);
    __builtin_amdgcn_s_setprio(0);
    __builtin_amdgcn_s_barrier();
    // ---- phase 1 ----
#pragma unroll
    for (int mr = 0; mr < 4; ++mr) {
      int r = wm * 128 + 64 + mr * 16 + (lane & 15);
#pragma unroll
      for (int ks = 0; ks < 2; ++ks) {
        int kg = ks * 4 + (lane >> 4);
        af[mr][ks] = *(const bf16x8*)(Ab + r * 128 + ((kg ^ (r & 7)) * 16));
      }
    }
    if (st) G2_STAGE_P1(pb, t + 2)
    LGKM0()
    __builtin_amdgcn_s_setprio(1);
#pragma unroll
    for (int mr = 0; mr < 4; ++mr)
#pragma unroll
      for (int nr = 0; nr < 2; ++nr)
#pragma unroll
        for (int ks = 0; ks < 2; ++ks)
          acc[4 + mr][nr] = __builtin_amdgcn_mfma_f32_16x16x32_bf16(af[mr][ks], bf[nr][ks], acc[4 + mr][nr], 0, 0, 0);
    __builtin_amdgcn_s_setprio(0);
  }
  // epilogue: col = n0 + wn*32 + nr*16 + (lane&15); 2 commutative atomics/elem
#pragma unroll
  for (int mr = 0; mr < 8; ++mr) {
#pragma unroll
    for (int j = 0; j < 4; ++j) {
      int rs = m0 + wm * 128 + mr * 16 + (lane >> 4) * 4 + j;
      if (rs < ce) {
        int tok = ptok[e * TTOK + rs];
        float gw = pw[e * TTOK + rs];
        float* orow = out + (size_t)tok * DEMB + n0 + wn * 32 + (lane & 15);
#pragma unroll
        for (int nr = 0; nr < 2; ++nr)
          atomicAdd(orow + nr * 16, acc[mr][nr][j] * gw);
      }
    }
  }
#undef G2_STAGE_P0
#undef G2_STAGE_P1
}

extern "C" void kernel_launch(void* const* d_in, const int* in_sizes, int n_in,
                              void* d_out, int out_size, void* d_ws, size_t ws_size,
                              hipStream_t stream) {
  const float* x  = (const float*)d_in[0];
  const float* wg = (const float*)d_in[1];
  const float* w1 = (const float*)d_in[2];
  const float* w2 = (const float*)d_in[3];
  const float* w3 = (const float*)d_in[4];
  char* ws = (char*)d_ws;
  int*   cnt  = (int*)(ws + OFF_CNT);
  int*   offs = (int*)(ws + OFF_OFFS);
  int*   ptok = (int*)(ws + OFF_PTOK);
  float* pw   = (float*)(ws + OFF_PW);
  unsigned short* Xb = (unsigned short*)(ws + OFF_XB);
  float* out = (float*)d_out;

  const size_t WPE = (size_t)HFF * DEMB;
  hipMemsetAsync(ws + OFF_CNT, 0, 256, stream);
  hipMemsetAsync(d_out, 0, (size_t)out_size * sizeof(float), stream);
  k_gate<<<TTOK / 4, 256, 0, stream>>>(x, wg, cnt, ptok, pw, Xb);
  k_scan<<<1, 64, 0, stream>>>(cnt, offs);

  size_t needA = OFF_WB + 3 * NEXP * WPE * 2 + (size_t)2 * TTOK * HFF * 2; // ~353MB
  if (ws_size >= needA) {
    unsigned short* w1b = (unsigned short*)(ws + OFF_WB);
    unsigned short* w3b = w1b + NEXP * WPE;
    unsigned short* w2b = w3b + NEXP * WPE;
    unsigned short* Hb  = w2b + NEXP * WPE;
    int cgrid = (int)(NEXP * WPE / 8 / 256);
    k_convert_w<<<cgrid, 256, 0, stream>>>(w1, (uint4*)w1b);
    k_convert_w<<<cgrid, 256, 0, stream>>>(w3, (uint4*)w3b);
    k_convert_w<<<cgrid, 256, 0, stream>>>(w2, (uint4*)w2b);
    // gemm1: 8e x 32mt(256 rows) x 64nt(64 hff cols) ; gemm2: 8e x 32mt x 8nt(128 cols)
    k_gemm1<<<NEXP * 32 * 64, 512, 0, stream>>>(Xb, w1b, w3b, cnt, offs, ptok, Hb, -1, 0, 32);
    k_gemm2<<<NEXP * 32 * 8, 512, 0, stream>>>(Hb, w2b, cnt, offs, ptok, pw, out, -1, 0, 32);
  } else {
    unsigned short* w1b = (unsigned short*)(ws + OFF_WB);
    unsigned short* w3b = w1b + WPE;
    unsigned short* w2b = w3b + WPE;
    unsigned short* Hb  = w2b + WPE;
    size_t offHbC = OFF_WB + 3 * WPE * 2;
    long long hbRows = ((long long)ws_size - (long long)offHbC) / (HFF * 2);
    int chunkTiles = (int)(hbRows / 256);
    if (chunkTiles < 1) chunkTiles = 1;
    if (chunkTiles > 32) chunkTiles = 32;
    int cgrid = (int)(WPE / 8 / 256);
    for (int e = 0; e < NEXP; ++e) {
      k_convert_w<<<cgrid, 256, 0, stream>>>(w1 + e * WPE, (uint4*)w1b);
      k_convert_w<<<cgrid, 256, 0, stream>>>(w3 + e * WPE, (uint4*)w3b);
      k_convert_w<<<cgrid, 256, 0, stream>>>(w2 + e * WPE, (uint4*)w2b);
      for (int mb = 0; mb < TTOK; mb += chunkTiles * 256) {
        int mT = chunkTiles;
        if (mb + mT * 256 > TTOK) mT = (TTOK - mb) / 256;
        if (mT < 1) break;
        k_gemm1<<<mT * 64, 512, 0, stream>>>(Xb, w1b, w3b, cnt, offs, ptok, Hb, e, mb, mT);
        k_gemm2<<<mT * 8, 512, 0, stream>>>(Hb, w2b, cnt, offs, ptok, pw, out, e, mb, mT);
      }
    }
  }
}

// Round 7
// 1100.351 us; speedup vs baseline: 1.0848x; 1.0848x over previous
//
#include <hip/hip_runtime.h>
#include <math.h>

// R7: identical to R5/R6 design (unbenched due to broker timeouts) — resubmitted.

#define NEXP 8
#define TTOK 8192
#define DEMB 1024
#define HFF  4096

// ws layout (bytes)
#define OFF_CNT   0
#define OFF_OFFS  64
#define OFF_PTOK  1024
#define OFF_PW    (OFF_PTOK + NEXP*TTOK*4)                 // 263,168
#define OFF_SID   (OFF_PW + NEXP*TTOK*4)                   // 525,312  (T*2 ints)
#define OFF_XB    (OFF_SID + TTOK*2*4)                     // 590,848
#define OFF_WB    (OFF_XB + (size_t)TTOK*DEMB*2)           // 17,368,064
// Tier A: Wb(201.3MB) + Hb(134.2MB) = ~352.9MB total. Ob (67.1MB fp32) aliases
// w1b (dead after gemm1; reconverted at the top of every call).

typedef short bf16x8 __attribute__((ext_vector_type(8)));
typedef float f32x4 __attribute__((ext_vector_type(4)));

__device__ __forceinline__ unsigned short f2bf(float f) {
  union { float f; unsigned int u; } v; v.f = f;
  unsigned int r = v.u + 0x7fffu + ((v.u >> 16) & 1u);
  return (unsigned short)(r >> 16);
}

__device__ __forceinline__ void gll16(const void* g, void* l) {
  __builtin_amdgcn_global_load_lds(
      (const __attribute__((address_space(1))) unsigned int*)g,
      (__attribute__((address_space(3))) unsigned int*)l, 16, 0, 0);
}

// ---------------- weights fp32 -> bf16 ----------------
__global__ void k_convert_w(const float* __restrict__ w, uint4* __restrict__ wb) {
  size_t i = (size_t)blockIdx.x * 256 + threadIdx.x;
  float4 a = ((const float4*)w)[2 * i];
  float4 b = ((const float4*)w)[2 * i + 1];
  uint4 o;
  o.x = (unsigned)f2bf(a.x) | ((unsigned)f2bf(a.y) << 16);
  o.y = (unsigned)f2bf(a.z) | ((unsigned)f2bf(a.w) << 16);
  o.z = (unsigned)f2bf(b.x) | ((unsigned)f2bf(b.y) << 16);
  o.w = (unsigned)f2bf(b.z) | ((unsigned)f2bf(b.w) << 16);
  wb[i] = o;
}

// ---------------- gating + top-2 + routing + X->bf16 ----------------
__global__ __launch_bounds__(256) void k_gate(
    const float* __restrict__ x, const float* __restrict__ wg,
    int* __restrict__ cnt, int* __restrict__ ptok, float* __restrict__ pw,
    int* __restrict__ sid, unsigned short* __restrict__ xb) {
  __shared__ float wgs[NEXP * DEMB];
  int tid = threadIdx.x;
  for (int i = tid; i < NEXP * DEMB / 4; i += 256)
    ((float4*)wgs)[i] = ((const float4*)wg)[i];
  __syncthreads();
  int lane = tid & 63;
  int t = blockIdx.x * 4 + (tid >> 6);
  const float* xr = x + (size_t)t * DEMB;
  unsigned short* xbr = xb + (size_t)t * DEMB;
  float acc[NEXP];
#pragma unroll
  for (int e = 0; e < NEXP; ++e) acc[e] = 0.f;
#pragma unroll
  for (int j = 0; j < 4; ++j) {
    int d = j * 256 + lane * 4;
    float4 v = *(const float4*)(xr + d);
    ushort4 o;
    o.x = f2bf(v.x); o.y = f2bf(v.y); o.z = f2bf(v.z); o.w = f2bf(v.w);
    *(ushort4*)(xbr + d) = o;
#pragma unroll
    for (int e = 0; e < NEXP; ++e) {
      float4 w = *(const float4*)(wgs + e * DEMB + d);
      acc[e] += v.x * w.x + v.y * w.y + v.z * w.z + v.w * w.w;
    }
  }
#pragma unroll
  for (int e = 0; e < NEXP; ++e) {
#pragma unroll
    for (int off = 32; off > 0; off >>= 1) acc[e] += __shfl_xor(acc[e], off);
  }
  if (lane == 0) {
    // top-2, lowest-index tie-break (matches lax.top_k)
    float b0 = -1e30f; int i0 = 0;
#pragma unroll
    for (int e = 0; e < NEXP; ++e) if (acc[e] > b0) { b0 = acc[e]; i0 = e; }
    float b1 = -1e30f; int i1 = 0;
#pragma unroll
    for (int e = 0; e < NEXP; ++e) if (e != i0 && acc[e] > b1) { b1 = acc[e]; i1 = e; }
    float ex = expf(b1 - b0);
    float s  = 1.f + ex;
    int s0 = atomicAdd(&cnt[i0], 1);
    ptok[i0 * TTOK + s0] = t; pw[i0 * TTOK + s0] = 1.f / s;
    int s1 = atomicAdd(&cnt[i1], 1);
    ptok[i1 * TTOK + s1] = t; pw[i1 * TTOK + s1] = ex / s;
    sid[2 * t]     = i0 * TTOK + s0;
    sid[2 * t + 1] = i1 * TTOK + s1;
  }
}

__global__ void k_scan(const int* __restrict__ cnt, int* __restrict__ offs) {
  if (threadIdx.x == 0) {
    int s = 0;
    for (int e = 0; e < NEXP; ++e) { offs[e] = s; s += cnt[e]; }
  }
}

// ---------------- combine: out[t] = Ob[row0] + Ob[row1] ----------------
__global__ void k_combine(const float* __restrict__ Ob, const int* __restrict__ sid,
                          const int* __restrict__ offs, float* __restrict__ out) {
  int idx = blockIdx.x * 256 + threadIdx.x;     // T * D/4 threads
  int t  = idx >> 8;                            // D/4 = 256 float4 per token
  int c4 = idx & 255;
  int s0 = sid[2 * t], s1 = sid[2 * t + 1];
  int r0 = offs[s0 / TTOK] + (s0 & (TTOK - 1));
  int r1 = offs[s1 / TTOK] + (s1 & (TTOK - 1));
  float4 a = ((const float4*)(Ob + (size_t)r0 * DEMB))[c4];
  float4 b = ((const float4*)(Ob + (size_t)r1 * DEMB))[c4];
  float4 o = {a.x + b.x, a.y + b.y, a.z + b.z, a.w + b.w};
  ((float4*)(out + (size_t)t * DEMB))[c4] = o;
}

// ---------------- GEMM1: h = silu(X@W1^T) * (X@W3^T) -> Hb (bf16) ----------------
// decode: mt fastest (64 consecutive blocks share the W1/W3 panel; Xb is L3-resident)
__global__ __launch_bounds__(256, 2) void k_gemm1(
    const unsigned short* __restrict__ Xb, const unsigned short* __restrict__ w1b,
    const unsigned short* __restrict__ w3b, const int* __restrict__ cnt,
    const int* __restrict__ offs, const int* __restrict__ ptok,
    unsigned short* __restrict__ Hb, int e_sel, int mbase, int mTiles) {
  int nwg = gridDim.x;
  int orig = blockIdx.x;
  int idp = (orig & 7) * (nwg >> 3) + (orig >> 3);  // bijective (nwg%8==0), XCD-contiguous
  int mt, e, nt;
  if (e_sel >= 0) { e = e_sel; mt = idp % mTiles; nt = idp / mTiles; }
  else { mt = idp % mTiles; e = (idp / mTiles) % NEXP; nt = idp / (mTiles * NEXP); }
  int ce = cnt[e];
  int m0 = mbase + mt * 128;
  if (m0 >= ce) return;
  int n0 = nt * 128;
  int hb = (e_sel >= 0) ? -mbase : offs[e];
  size_t eo = (size_t)((e_sel >= 0) ? 0 : e) * HFF * DEMB;
  const unsigned short* w1e = w1b + eo;
  const unsigned short* w3e = w3b + eo;

  __shared__ __align__(16) unsigned char sm[49152];
  unsigned char* As = sm;            // 128x64 bf16, involution-swizzled
  unsigned char* B1 = sm + 16384;
  unsigned char* B3 = sm + 32768;

  int tid = threadIdx.x, lane = tid & 63, wid = tid >> 6;
  int wm = (wid >> 1) * 64, wn = (wid & 1) * 64;

  const unsigned short *as[4], *b1s[4], *b3s[4];
#pragma unroll
  for (int it = 0; it < 4; ++it) {
    int c = it * 256 + tid;
    int row = c >> 3;
    int col = ((c & 7) ^ (row & 7)) * 8;
    int slot = m0 + row; slot = slot < ce ? slot : ce - 1;
    int tok = ptok[e * TTOK + slot];
    as[it]  = Xb + (size_t)tok * DEMB + col;
    b1s[it] = w1e + (size_t)(n0 + row) * DEMB + col;
    b3s[it] = w3e + (size_t)(n0 + row) * DEMB + col;
  }

  const f32x4 zf = {0.f, 0.f, 0.f, 0.f};
  f32x4 au[4][4], av[4][4];
#pragma unroll
  for (int a = 0; a < 4; ++a)
#pragma unroll
    for (int b = 0; b < 4; ++b) { au[a][b] = zf; av[a][b] = zf; }

  for (int kt = 0; kt < DEMB / 64; ++kt) {
    int k0 = kt * 64;
#pragma unroll
    for (int it = 0; it < 4; ++it) gll16(as[it] + k0,  As + it * 4096 + wid * 1024);
#pragma unroll
    for (int it = 0; it < 4; ++it) gll16(b1s[it] + k0, B1 + it * 4096 + wid * 1024);
#pragma unroll
    for (int it = 0; it < 4; ++it) gll16(b3s[it] + k0, B3 + it * 4096 + wid * 1024);
    __syncthreads();
#pragma unroll
    for (int kk = 0; kk < 64; kk += 32) {
      bf16x8 af[4], b1f[4], b3f[4];
      int kg = (kk >> 3) + (lane >> 4);
#pragma unroll
      for (int mr = 0; mr < 4; ++mr) {
        int r = wm + mr * 16 + (lane & 15);
        af[mr] = *(const bf16x8*)(As + r * 128 + ((kg ^ (r & 7)) * 16));
      }
#pragma unroll
      for (int nr = 0; nr < 4; ++nr) {
        int c = wn + nr * 16 + (lane & 15);
        int boff = c * 128 + ((kg ^ (c & 7)) * 16);
        b1f[nr] = *(const bf16x8*)(B1 + boff);
        b3f[nr] = *(const bf16x8*)(B3 + boff);
      }
#pragma unroll
      for (int mr = 0; mr < 4; ++mr)
#pragma unroll
        for (int nr = 0; nr < 4; ++nr) {
          au[mr][nr] = __builtin_amdgcn_mfma_f32_16x16x32_bf16(af[mr], b1f[nr], au[mr][nr], 0, 0, 0);
          av[mr][nr] = __builtin_amdgcn_mfma_f32_16x16x32_bf16(af[mr], b3f[nr], av[mr][nr], 0, 0, 0);
        }
    }
    __syncthreads();
  }
  // epilogue: silu(u)*v -> bf16 Hb ; C layout: col=lane&15, row=(lane>>4)*4+j
#pragma unroll
  for (int mr = 0; mr < 4; ++mr) {
#pragma unroll
    for (int j = 0; j < 4; ++j) {
      int rs = m0 + wm + mr * 16 + (lane >> 4) * 4 + j;
      if (rs < ce) {
        unsigned short* hrow = Hb + (size_t)(hb + rs) * HFF + n0 + wn + (lane & 15);
#pragma unroll
        for (int nr = 0; nr < 4; ++nr) {
          float u = au[mr][nr][j], v = av[mr][nr][j];
          float h = v * (u / (1.f + __expf(-u)));
          hrow[nr * 16] = f2bf(h);
        }
      }
    }
  }
}

// ---------------- GEMM2: Ob[slot] = gate_w * (H @ W2^T)  (or atomic into out) ----------------
// decode: nt fastest (8 consecutive blocks share the same Hb A-panel -> L2 reuse)
__global__ __launch_bounds__(256, 2) void k_gemm2(
    const unsigned short* __restrict__ Hb, const unsigned short* __restrict__ w2b,
    const int* __restrict__ cnt, const int* __restrict__ offs,
    const int* __restrict__ ptok, const float* __restrict__ pw,
    float* __restrict__ out, float* __restrict__ Ob,
    int e_sel, int mbase, int mTiles) {
  int nwg = gridDim.x;
  int orig = blockIdx.x;
  int idp = (orig & 7) * (nwg >> 3) + (orig >> 3);
  int nt = idp & 7;                 // DEMB/128 = 8 n-tiles, fastest
  int r  = idp >> 3;
  int mt, e;
  if (e_sel >= 0) { e = e_sel; mt = r; }
  else { mt = r % mTiles; e = r / mTiles; }
  int ce = cnt[e];
  int m0 = mbase + mt * 128;
  if (m0 >= ce) return;
  int n0 = nt * 128;
  int hb = (e_sel >= 0) ? -mbase : offs[e];
  size_t eo = (size_t)((e_sel >= 0) ? 0 : e) * DEMB * HFF;
  const unsigned short* w2e = w2b + eo;

  __shared__ __align__(16) unsigned char sm[32768];
  unsigned char* As = sm;
  unsigned char* B2 = sm + 16384;

  int tid = threadIdx.x, lane = tid & 63, wid = tid >> 6;
  int wm = (wid >> 1) * 64, wn = (wid & 1) * 64;

  const unsigned short *as[4], *b2s[4];
#pragma unroll
  for (int it = 0; it < 4; ++it) {
    int c = it * 256 + tid;
    int row = c >> 3;
    int col = ((c & 7) ^ (row & 7)) * 8;
    int slot = m0 + row; slot = slot < ce ? slot : ce - 1;
    as[it]  = Hb + (size_t)(hb + slot) * HFF + col;
    b2s[it] = w2e + (size_t)(n0 + row) * HFF + col;
  }

  const f32x4 zf = {0.f, 0.f, 0.f, 0.f};
  f32x4 acc[4][4];
#pragma unroll
  for (int a = 0; a < 4; ++a)
#pragma unroll
    for (int b = 0; b < 4; ++b) acc[a][b] = zf;

  for (int kt = 0; kt < HFF / 64; ++kt) {
    int k0 = kt * 64;
#pragma unroll
    for (int it = 0; it < 4; ++it) gll16(as[it] + k0,  As + it * 4096 + wid * 1024);
#pragma unroll
    for (int it = 0; it < 4; ++it) gll16(b2s[it] + k0, B2 + it * 4096 + wid * 1024);
    __syncthreads();
#pragma unroll
    for (int kk = 0; kk < 64; kk += 32) {
      bf16x8 af[4], bf_[4];
      int kg = (kk >> 3) + (lane >> 4);
#pragma unroll
      for (int mr = 0; mr < 4; ++mr) {
        int r2 = wm + mr * 16 + (lane & 15);
        af[mr] = *(const bf16x8*)(As + r2 * 128 + ((kg ^ (r2 & 7)) * 16));
      }
#pragma unroll
      for (int nr = 0; nr < 4; ++nr) {
        int c = wn + nr * 16 + (lane & 15);
        bf_[nr] = *(const bf16x8*)(B2 + c * 128 + ((kg ^ (c & 7)) * 16));
      }
#pragma unroll
      for (int mr = 0; mr < 4; ++mr)
#pragma unroll
        for (int nr = 0; nr < 4; ++nr)
          acc[mr][nr] = __builtin_amdgcn_mfma_f32_16x16x32_bf16(af[mr], bf_[nr], acc[mr][nr], 0, 0, 0);
    }
    __syncthreads();
  }
  // epilogue
#pragma unroll
  for (int mr = 0; mr < 4; ++mr) {
#pragma unroll
    for (int j = 0; j < 4; ++j) {
      int rs = m0 + wm + mr * 16 + (lane >> 4) * 4 + j;
      if (rs < ce) {
        float gw = pw[e * TTOK + rs];
        if (Ob) {
          float* orow = Ob + (size_t)(hb + rs) * DEMB + n0 + wn + (lane & 15);
#pragma unroll
          for (int nr = 0; nr < 4; ++nr) orow[nr * 16] = acc[mr][nr][j] * gw;
        } else {
          int tok = ptok[e * TTOK + rs];
          float* orow = out + (size_t)tok * DEMB + n0 + wn + (lane & 15);
#pragma unroll
          for (int nr = 0; nr < 4; ++nr) atomicAdd(orow + nr * 16, acc[mr][nr][j] * gw);
        }
      }
    }
  }
}

extern "C" void kernel_launch(void* const* d_in, const int* in_sizes, int n_in,
                              void* d_out, int out_size, void* d_ws, size_t ws_size,
                              hipStream_t stream) {
  const float* x  = (const float*)d_in[0];
  const float* wg = (const float*)d_in[1];
  const float* w1 = (const float*)d_in[2];
  const float* w2 = (const float*)d_in[3];
  const float* w3 = (const float*)d_in[4];
  char* ws = (char*)d_ws;
  int*   cnt  = (int*)(ws + OFF_CNT);
  int*   offs = (int*)(ws + OFF_OFFS);
  int*   ptok = (int*)(ws + OFF_PTOK);
  float* pw   = (float*)(ws + OFF_PW);
  int*   sid  = (int*)(ws + OFF_SID);
  unsigned short* Xb = (unsigned short*)(ws + OFF_XB);
  float* out = (float*)d_out;

  const size_t WPE = (size_t)HFF * DEMB;
  hipMemsetAsync(ws + OFF_CNT, 0, 256, stream);
  k_gate<<<TTOK / 4, 256, 0, stream>>>(x, wg, cnt, ptok, pw, sid, Xb);
  k_scan<<<1, 64, 0, stream>>>(cnt, offs);

  size_t needA = OFF_WB + 3 * NEXP * WPE * 2 + (size_t)2 * TTOK * HFF * 2; // ~352.9MB
  if (ws_size >= needA) {
    // Tier A: Ob (fp32, 67.1MB) aliases w1b (dead after gemm1; reconverted every call)
    unsigned short* w1b = (unsigned short*)(ws + OFF_WB);
    unsigned short* w3b = w1b + NEXP * WPE;
    unsigned short* w2b = w3b + NEXP * WPE;
    unsigned short* Hb  = w2b + NEXP * WPE;
    float* Ob = (float*)w1b;
    int cgrid = (int)(NEXP * WPE / 8 / 256);
    k_convert_w<<<cgrid, 256, 0, stream>>>(w1, (uint4*)w1b);
    k_convert_w<<<cgrid, 256, 0, stream>>>(w3, (uint4*)w3b);
    k_convert_w<<<cgrid, 256, 0, stream>>>(w2, (uint4*)w2b);
    k_gemm1<<<NEXP * 64 * 32, 256, 0, stream>>>(Xb, w1b, w3b, cnt, offs, ptok, Hb, -1, 0, 64);
    k_gemm2<<<NEXP * 64 * 8, 256, 0, stream>>>(Hb, w2b, cnt, offs, ptok, pw, out, Ob, -1, 0, 64);
    k_combine<<<TTOK * (DEMB / 4) / 256, 256, 0, stream>>>(Ob, sid, offs, out);
  } else {
    // Tier C: per-expert loop, atomic epilogue into out
    hipMemsetAsync(d_out, 0, (size_t)out_size * sizeof(float), stream);
    unsigned short* w1b = (unsigned short*)(ws + OFF_WB);
    unsigned short* w3b = w1b + WPE;
    unsigned short* w2b = w3b + WPE;
    unsigned short* Hb  = w2b + WPE;
    size_t offHbC = OFF_WB + 3 * WPE * 2;
    long long hbRows = ((long long)ws_size - (long long)offHbC) / (HFF * 2);
    int chunkTiles = (int)(hbRows / 128);
    if (chunkTiles < 1) chunkTiles = 1;
    if (chunkTiles > 64) chunkTiles = 64;
    int cgrid = (int)(WPE / 8 / 256);
    for (int e = 0; e < NEXP; ++e) {
      k_convert_w<<<cgrid, 256, 0, stream>>>(w1 + e * WPE, (uint4*)w1b);
      k_convert_w<<<cgrid, 256, 0, stream>>>(w3 + e * WPE, (uint4*)w3b);
      k_convert_w<<<cgrid, 256, 0, stream>>>(w2 + e * WPE, (uint4*)w2b);
      for (int mb = 0; mb < TTOK; mb += chunkTiles * 128) {
        int mT = chunkTiles;
        if (mb + mT * 128 > TTOK) mT = (TTOK - mb) / 128;
        if (mT < 1) break;
        k_gemm1<<<mT * 32, 256, 0, stream>>>(Xb, w1b, w3b, cnt, offs, ptok, Hb, e, mb, mT);
        k_gemm2<<<mT * 8, 256, 0, stream>>>(Hb, w2b, cnt, offs, ptok, pw, out, (float*)0, e, mb, mT);
      }
    }
  }
}